// Round 3
// baseline (146.960 us; speedup 1.0000x reference)
//
#include <hip/hip_runtime.h>

typedef unsigned char u8;
typedef float fp32x4 __attribute__((ext_vector_type(4)));
typedef long lx2 __attribute__((ext_vector_type(2)));

#define BS 4096
#define NROW 8192
#define D 512
#define TILE 128
#define NB (NROW / TILE)          // 64 block-rows/cols
#define NBLK (NB * (NB + 1) / 2)  // 2080 upper-triangle tiles
#define NPBLK 256                 // persistent workgroups (1 per CU)
#define NTHR 512                  // 8 waves -> 2 waves/SIMD
#define INV_T 10.0f

// Packed An layout (producer + staging + consumer all agree; staging is a
// LINEAR byte copy so the permutation lives only in this formula).
// 8-byte chunk L = k>>3 of row r lives at:
//   off(r, L) = (r>>4)*8192 + (L>>3)*1024 + (r&15)*64
//             + (((L&3) ^ ((r&15)>>2)) << 4) + (((L>>2)&1) << 3)
// Consumer: lane (fr=l&15, h=l>>4) reads ONE ds_read_b128 per (row16, p)
// covering ks=2p,2p+1 at  rowgrp*8192 + p*1024 + fr*64 + ((h^(fr>>2))&3)*16.
// Per 16-lane quarter the chunk residues mod 8 are bijective -> every bank
// gets exactly 2 words = structural floor, 0 conflicts (verified R2:
// SQ_LDS_BANK_CONFLICT 1.28e7 -> 2.1e6).

__device__ __forceinline__ void g2l16(const void* g, void* l) {
  __builtin_amdgcn_global_load_lds(
      (const __attribute__((address_space(1))) unsigned int*)g,
      (__attribute__((address_space(3))) unsigned int*)l, 16, 0, 0);
}

// stage one 128-row strip (64 KB contiguous) into LDS; 8 g2l16 per thread
__device__ __forceinline__ void stage_strip(const u8* __restrict__ g,
                                            u8* __restrict__ l, int tid) {
#pragma unroll
  for (int it = 0; it < 8; ++it)
    g2l16(g + it * 8192 + tid * 16, l + it * 8192 + tid * 16);
}

// Wave-per-row normalize -> fp8 e4m3, written in packed+swizzled layout.
// Also zeroes den/posAcc/done (ws is re-poisoned before every launch).
__global__ __launch_bounds__(256) void normalize_k(
    const float* __restrict__ zi, const float* __restrict__ zj,
    u8* __restrict__ An, float* __restrict__ den, float* __restrict__ posAcc,
    int* __restrict__ done) {
  const int lane = threadIdx.x & 63;
  const int wave = threadIdx.x >> 6;
  const int r = blockIdx.x * 4 + wave;
  const float* src = (r < BS) ? (zi + (size_t)r * D) : (zj + (size_t)(r - BS) * D);
  const float4 v0 = ((const float4*)src)[lane * 2];
  const float4 v1 = ((const float4*)src)[lane * 2 + 1];
  float ss = v0.x * v0.x + v0.y * v0.y + v0.z * v0.z + v0.w * v0.w +
             v1.x * v1.x + v1.y * v1.y + v1.z * v1.z + v1.w * v1.w;
#pragma unroll
  for (int off = 1; off < 64; off <<= 1) ss += __shfl_xor(ss, off);
  const float inv = 1.0f / fmaxf(sqrtf(ss), 1e-8f);
  int lo = __builtin_amdgcn_cvt_pk_fp8_f32(v0.x * inv, v0.y * inv, 0, false);
  lo = __builtin_amdgcn_cvt_pk_fp8_f32(v0.z * inv, v0.w * inv, lo, true);
  int hi = __builtin_amdgcn_cvt_pk_fp8_f32(v1.x * inv, v1.y * inv, 0, false);
  hi = __builtin_amdgcn_cvt_pk_fp8_f32(v1.z * inv, v1.w * inv, hi, true);
  // lane holds chunk L = lane (k = 8*lane .. +8)
  const int r16 = r & 15;
  const int off = ((r >> 4) << 13) + ((lane >> 3) << 10) + (r16 << 6) +
                  ((((lane & 3) ^ (r16 >> 2)) & 3) << 4) + (((lane >> 2) & 1) << 3);
  *(int2*)(An + off) = make_int2(lo, hi);
  if (lane == 0) den[r] = 0.0f;
  if (r == 0 && lane == 0) { posAcc[0] = 0.0f; *done = 0; }
}

// Persistent full-K GEMM, 8 waves (2/SIMD for latency hiding). Each block
// owns a contiguous chunk of ~8 triangle tiles. LDS holds full-K A and B
// strips -> zero barriers inside the K loop. Per tile:
//   compute -> barrier -> issue next-tile DMA -> epilogue (overlaps DMA)
//   -> barrier. A-strip restaged only when bi changes.
// The LAST block to finish also does the log-sum finalize (device-scope
// atomics make den/posAcc coherent across XCDs).
__global__ __launch_bounds__(NTHR) void gemm_expsum(
    const u8* __restrict__ An, float* __restrict__ den,
    float* __restrict__ posAcc, int* __restrict__ done,
    float* __restrict__ out) {
  __shared__ __align__(16) u8 sA[TILE * D];  // 64 KB
  __shared__ __align__(16) u8 sB[TILE * D];  // 64 KB
  __shared__ float redbuf[8];
  __shared__ int lastFlag;

  const int tid = threadIdx.x;
  const int lane = tid & 63;
  const int wave = tid >> 6;
  const int wr = wave >> 1;  // 0..3 : 32-row band within the 128x128 tile
  const int wc = wave & 1;   // 0..1 : 64-col band
  const int fr = lane & 15;
  const int h = lane >> 4;

  // contiguous chunk [t0, t1) of triangle tiles (8 or 9 per block)
  const int t0 = (int)(((long)blockIdx.x * NBLK) >> 8);
  const int t1 = (int)(((long)(blockIdx.x + 1) * NBLK) >> 8);

  int rem = t0, bi = 0;
  while (rem >= NB - bi) { rem -= NB - bi; ++bi; }
  int bj = bi + rem;

  stage_strip(An + (size_t)bi * 65536, sA, tid);
  stage_strip(An + (size_t)bj * 65536, sB, tid);
  __syncthreads();  // drains vmcnt -> tiles resident

  // per-lane fragment base: one b128 per (rowgrp, p) covers ks=2p, 2p+1
  const int fbase = fr * 64 + ((h ^ (fr >> 2)) & 3) * 16;
  const u8* pa = sA + wr * 16384 + fbase;
  const u8* pb = sB + wc * 32768 + fbase;

  for (int t = t0; t < t1; ++t) {
    fp32x4 acc[2][4] = {};
    // full-K compute: no barriers; 48 ds_read_b128 + 128 MFMA per wave
#pragma unroll
    for (int p = 0; p < 8; ++p) {
      lx2 a[2], b[4];
#pragma unroll
      for (int i = 0; i < 2; ++i) a[i] = *(const lx2*)(pa + i * 8192 + p * 1024);
#pragma unroll
      for (int j = 0; j < 4; ++j) b[j] = *(const lx2*)(pb + j * 8192 + p * 1024);
#pragma unroll
      for (int i = 0; i < 2; ++i)
#pragma unroll
        for (int j = 0; j < 4; ++j)
          acc[i][j] = __builtin_amdgcn_mfma_f32_16x16x32_fp8_fp8(
              a[i][0], b[j][0], acc[i][j], 0, 0, 0);
#pragma unroll
      for (int i = 0; i < 2; ++i)
#pragma unroll
        for (int j = 0; j < 4; ++j)
          acc[i][j] = __builtin_amdgcn_mfma_f32_16x16x32_fp8_fp8(
              a[i][1], b[j][1], acc[i][j], 0, 0, 0);
    }
    __syncthreads();  // every wave done reading sA/sB

    // issue next tile's staging NOW; the DMA runs under the epilogue below
    int nbi = bi, nbj = bj + 1;
    if (nbj == NB) { ++nbi; nbj = nbi; }
    if (t + 1 < t1) {
      if (nbi != bi) stage_strip(An + (size_t)nbi * 65536, sA, tid);
      stage_strip(An + (size_t)nbj * 65536, sB, tid);
    }

    // Epilogue (register-only + atomics; safe while DMA overwrites LDS).
    // C/D layout: col = lane&15, row = (lane>>4)*4 + reg.
    const bool diag = (bi == bj);
    const int rowBase = bi * TILE;
    const int colBase = bj * TILE;
    const int rq = h * 4;
    float posPart = 0.0f;
    float colAcc[4] = {0.0f, 0.0f, 0.0f, 0.0f};
#pragma unroll
    for (int i = 0; i < 2; ++i) {
      const int rbase = rowBase + wr * 32 + i * 16 + rq;
      float rs[4] = {0.0f, 0.0f, 0.0f, 0.0f};
#pragma unroll
      for (int j = 0; j < 4; ++j) {
        const int colg = colBase + wc * 64 + j * 16 + fr;
        fp32x4 v = acc[i][j];
#pragma unroll
        for (int rg = 0; rg < 4; ++rg) {
          const int rowg = rbase + rg;
          const float sv = v[rg] * INV_T;
          float e = __expf(sv);
          if (diag && rowg == colg) e = 0.0f;  // exclude exact diagonal
          rs[rg] += e;
          colAcc[j] += e;
          if (colg == rowg + BS) posPart += sv;  // upper copy; doubled later
        }
      }
#pragma unroll
      for (int rg = 0; rg < 4; ++rg) {
        float s = rs[rg];
        s += __shfl_xor(s, 1);
        s += __shfl_xor(s, 2);
        s += __shfl_xor(s, 4);
        s += __shfl_xor(s, 8);
        if (fr == 0) atomicAdd(&den[rbase + rg], s);
      }
    }
    if (!diag) {
#pragma unroll
      for (int j = 0; j < 4; ++j) {
        float c = colAcc[j];
        c += __shfl_xor(c, 16);
        c += __shfl_xor(c, 32);
        if (h == 0) atomicAdd(&den[colBase + wc * 64 + j * 16 + fr], c);
      }
    }
    posPart += __shfl_xor(posPart, 1);
    posPart += __shfl_xor(posPart, 2);
    posPart += __shfl_xor(posPart, 4);
    posPart += __shfl_xor(posPart, 8);
    posPart += __shfl_xor(posPart, 16);
    posPart += __shfl_xor(posPart, 32);
    if (lane == 0 && posPart != 0.0f) atomicAdd(posAcc, posPart);

    __syncthreads();  // drains vmcnt -> next tile staged; LDS reuse safe
    bi = nbi;
    bj = nbj;
  }

  // ---- fused finalize: last block to finish computes the loss ----
  __threadfence();  // device-scope: den/posAcc atomics visible
  if (tid == 0) lastFlag = (atomicAdd(done, 1) == NPBLK - 1);
  __syncthreads();
  if (lastFlag) {
    float s = 0.0f;
    for (int i = tid; i < NROW; i += NTHR)
      s += logf(__hip_atomic_load(&den[i], __ATOMIC_RELAXED,
                                  __HIP_MEMORY_SCOPE_AGENT));
#pragma unroll
    for (int off = 1; off < 64; off <<= 1) s += __shfl_xor(s, off);
    if (lane == 0) redbuf[wave] = s;
    __syncthreads();
    if (tid == 0) {
      float tot = 0.0f;
#pragma unroll
      for (int w = 0; w < 8; ++w) tot += redbuf[w];
      const float pos = __hip_atomic_load(posAcc, __ATOMIC_RELAXED,
                                          __HIP_MEMORY_SCOPE_AGENT);
      // each unordered positive pair was counted once -> double it
      out[0] = (tot - 2.0f * pos) * (1.0f / (float)NROW);
    }
  }
}

extern "C" void kernel_launch(void* const* d_in, const int* in_sizes, int n_in,
                              void* d_out, int out_size, void* d_ws, size_t ws_size,
                              hipStream_t stream) {
  const float* zi = (const float*)d_in[0];
  const float* zj = (const float*)d_in[1];
  float* out = (float*)d_out;

  u8* An = (u8*)d_ws;                                      // 4 MB packed fp8
  float* den = (float*)((char*)d_ws + (size_t)NROW * D);   // 8192 fp32
  float* posAcc = den + NROW;                              // 1 fp32
  int* done = (int*)(posAcc + 1);                          // 1 int

  normalize_k<<<NROW / 4, 256, 0, stream>>>(zi, zj, An, den, posAcc, done);
  gemm_expsum<<<NPBLK, NTHR, 0, stream>>>(An, den, posAcc, done, out);
}

// Round 4
// 138.340 us; speedup vs baseline: 1.0623x; 1.0623x over previous
//
#include <hip/hip_runtime.h>

typedef unsigned char u8;
typedef float fp32x4 __attribute__((ext_vector_type(4)));
typedef long lx2 __attribute__((ext_vector_type(2)));

#define BS 4096
#define NROW 8192
#define D 512
#define TILE 128
#define NB (NROW / TILE)          // 64 block-rows/cols
#define NBLK (NB * (NB + 1) / 2)  // 2080 upper-triangle tiles
#define NPBLK 512                 // 2 blocks/CU (64.1 KB LDS each)
#define NTHR 256                  // 4 waves
#define INV_T 10.0f

// Packed An layout (producer + staging + consumer agree; staging is a LINEAR
// byte copy so the permutation lives only in this formula).
// 8-byte chunk L = k>>3 of row r lives at:
//   off(r, L) = (r>>4)*8192 + (L>>3)*1024 + (r&15)*64
//             + (((L&3) ^ ((r&15)>>2)) << 4) + (((L>>2)&1) << 3)
// Consumer: lane (fr=l&15, h=l>>4) reads ONE b128 per (rowgrp, p) covering
// ks=2p,2p+1 at  rowgrp*8192 + p*1024 + fr*64 + ((h^(fr>>2))&3)*16.
//  - LDS (A): per 16-lane quarter the word residues mod 32 are bijective ->
//    2 words/bank uniform = structural floor (verified R2: 1.28e7 -> 2.1e6).
//  - Global (B): fr*64 + swz*16 is a bijection onto [0,1024) -> each wave
//    reads exactly one contiguous 1 KB p-block = perfectly coalesced
//    global_load_dwordx4 from L2 (An is 4 MB, L2-resident; FETCH ~16 MB).

__device__ __forceinline__ void g2l16(const void* g, void* l) {
  __builtin_amdgcn_global_load_lds(
      (const __attribute__((address_space(1))) unsigned int*)g,
      (__attribute__((address_space(3))) unsigned int*)l, 16, 0, 0);
}

// stage one 128-row strip (64 KB contiguous) into LDS; 16 g2l16 per thread
__device__ __forceinline__ void stage_strip(const u8* __restrict__ g,
                                            u8* __restrict__ l, int tid) {
#pragma unroll
  for (int it = 0; it < 16; ++it)
    g2l16(g + it * 4096 + tid * 16, l + it * 4096 + tid * 16);
}

// Wave-per-row normalize -> fp8 e4m3, written in packed+swizzled layout.
// Also zeroes den/posAcc/done (ws is re-poisoned before every launch).
__global__ __launch_bounds__(256) void normalize_k(
    const float* __restrict__ zi, const float* __restrict__ zj,
    u8* __restrict__ An, float* __restrict__ den, float* __restrict__ posAcc,
    int* __restrict__ done) {
  const int lane = threadIdx.x & 63;
  const int wave = threadIdx.x >> 6;
  const int r = blockIdx.x * 4 + wave;
  const float* src = (r < BS) ? (zi + (size_t)r * D) : (zj + (size_t)(r - BS) * D);
  const float4 v0 = ((const float4*)src)[lane * 2];
  const float4 v1 = ((const float4*)src)[lane * 2 + 1];
  float ss = v0.x * v0.x + v0.y * v0.y + v0.z * v0.z + v0.w * v0.w +
             v1.x * v1.x + v1.y * v1.y + v1.z * v1.z + v1.w * v1.w;
#pragma unroll
  for (int off = 1; off < 64; off <<= 1) ss += __shfl_xor(ss, off);
  const float inv = 1.0f / fmaxf(sqrtf(ss), 1e-8f);
  int lo = __builtin_amdgcn_cvt_pk_fp8_f32(v0.x * inv, v0.y * inv, 0, false);
  lo = __builtin_amdgcn_cvt_pk_fp8_f32(v0.z * inv, v0.w * inv, lo, true);
  int hi = __builtin_amdgcn_cvt_pk_fp8_f32(v1.x * inv, v1.y * inv, 0, false);
  hi = __builtin_amdgcn_cvt_pk_fp8_f32(v1.z * inv, v1.w * inv, hi, true);
  // lane holds chunk L = lane (k = 8*lane .. +8)
  const int r16 = r & 15;
  const int off = ((r >> 4) << 13) + ((lane >> 3) << 10) + (r16 << 6) +
                  ((((lane & 3) ^ (r16 >> 2)) & 3) << 4) + (((lane >> 2) & 1) << 3);
  *(int2*)(An + off) = make_int2(lo, hi);
  if (lane == 0) den[r] = 0.0f;
  if (r == 0 && lane == 0) { posAcc[0] = 0.0f; *done = 0; }
}

// Persistent triangle GEMM, 4 waves, 2 independent blocks/CU.
// LDS holds ONLY the A strip (full K, 64 KB) -> B fragments are read
// directly from L2 (coalesced 1KB/wave loads, p+1 prefetched). The K loop
// and the tile loop have ZERO barriers; syncs only when bi changes.
// Last block to finish computes the loss (device-scope atomics).
__global__ __launch_bounds__(NTHR) void gemm_expsum(
    const u8* __restrict__ An, float* __restrict__ den,
    float* __restrict__ posAcc, int* __restrict__ done,
    float* __restrict__ out) {
  __shared__ __align__(16) u8 sA[TILE * D];  // 64 KB
  __shared__ float redbuf[4];
  __shared__ int lastFlag;

  const int tid = threadIdx.x;
  const int lane = tid & 63;
  const int wave = tid >> 6;
  const int wr = wave >> 1;  // 64-row band within the 128x128 tile
  const int wc = wave & 1;   // 64-col band
  const int fr = lane & 15;
  const int h = lane >> 4;

  // contiguous chunk [t0, t1) of triangle tiles (4 or 5 per block)
  const int t0 = (int)(((long)blockIdx.x * NBLK) >> 9);
  const int t1 = (int)(((long)(blockIdx.x + 1) * NBLK) >> 9);

  int rem = t0, bi = 0;
  while (rem >= NB - bi) { rem -= NB - bi; ++bi; }
  int bj = bi + rem;

  stage_strip(An + (size_t)bi * 65536, sA, tid);
  __syncthreads();  // drains vmcnt -> A strip resident

  // per-lane fragment base: one b128 per (rowgrp, p) covers ks=2p, 2p+1
  const int fbase = fr * 64 + ((h ^ (fr >> 2)) & 3) * 16;
  const u8* pa = sA + wr * 32768 + fbase;

  for (int t = t0; t < t1; ++t) {
    const u8* gb = An + (size_t)bj * 65536 + wc * 32768 + fbase;
    fp32x4 acc[4][4] = {};
    lx2 bc[4], bn[4];
#pragma unroll
    for (int j = 0; j < 4; ++j) bc[j] = *(const lx2*)(gb + j * 8192);
    // full-K compute: no barriers; A from LDS, B streamed from L2 with
    // one-step prefetch
#pragma unroll
    for (int p = 0; p < 8; ++p) {
      if (p < 7) {
#pragma unroll
        for (int j = 0; j < 4; ++j)
          bn[j] = *(const lx2*)(gb + j * 8192 + (p + 1) * 1024);
      }
      lx2 a[4];
#pragma unroll
      for (int i = 0; i < 4; ++i) a[i] = *(const lx2*)(pa + i * 8192 + p * 1024);
#pragma unroll
      for (int i = 0; i < 4; ++i)
#pragma unroll
        for (int j = 0; j < 4; ++j)
          acc[i][j] = __builtin_amdgcn_mfma_f32_16x16x32_fp8_fp8(
              a[i][0], bc[j][0], acc[i][j], 0, 0, 0);
#pragma unroll
      for (int i = 0; i < 4; ++i)
#pragma unroll
        for (int j = 0; j < 4; ++j)
          acc[i][j] = __builtin_amdgcn_mfma_f32_16x16x32_fp8_fp8(
              a[i][1], bc[j][1], acc[i][j], 0, 0, 0);
#pragma unroll
      for (int j = 0; j < 4; ++j) bc[j] = bn[j];
    }

    // Epilogue (register-only + atomics; no LDS hazard -> no barrier).
    // C/D layout: col = lane&15, row = (lane>>4)*4 + reg.
    const bool diag = (bi == bj);
    const int rowBase = bi * TILE;
    const int colBase = bj * TILE;
    const int rq = h * 4;
    float posPart = 0.0f;
    float colAcc[4] = {0.0f, 0.0f, 0.0f, 0.0f};
#pragma unroll
    for (int i = 0; i < 4; ++i) {
      const int rbase = rowBase + wr * 64 + i * 16 + rq;
      float rs[4] = {0.0f, 0.0f, 0.0f, 0.0f};
#pragma unroll
      for (int j = 0; j < 4; ++j) {
        const int colg = colBase + wc * 64 + j * 16 + fr;
        fp32x4 v = acc[i][j];
#pragma unroll
        for (int rg = 0; rg < 4; ++rg) {
          const int rowg = rbase + rg;
          const float sv = v[rg] * INV_T;
          float e = __expf(sv);
          if (diag && rowg == colg) e = 0.0f;  // exclude exact diagonal
          rs[rg] += e;
          colAcc[j] += e;
          if (colg == rowg + BS) posPart += sv;  // upper copy; doubled later
        }
      }
#pragma unroll
      for (int rg = 0; rg < 4; ++rg) {
        float s = rs[rg];
        s += __shfl_xor(s, 1);
        s += __shfl_xor(s, 2);
        s += __shfl_xor(s, 4);
        s += __shfl_xor(s, 8);
        if (fr == 0) atomicAdd(&den[rbase + rg], s);
      }
    }
    if (!diag) {
#pragma unroll
      for (int j = 0; j < 4; ++j) {
        float c = colAcc[j];
        c += __shfl_xor(c, 16);
        c += __shfl_xor(c, 32);
        if (h == 0) atomicAdd(&den[colBase + wc * 64 + j * 16 + fr], c);
      }
    }
    posPart += __shfl_xor(posPart, 1);
    posPart += __shfl_xor(posPart, 2);
    posPart += __shfl_xor(posPart, 4);
    posPart += __shfl_xor(posPart, 8);
    posPart += __shfl_xor(posPart, 16);
    posPart += __shfl_xor(posPart, 32);
    if (lane == 0 && posPart != 0.0f) atomicAdd(posAcc, posPart);

    // advance; restage A only when the row band changes
    ++bj;
    if (bj == NB) {
      ++bi;
      bj = bi;
      if (t + 1 < t1) {
        __syncthreads();  // all waves done reading old sA
        stage_strip(An + (size_t)bi * 65536, sA, tid);
        __syncthreads();  // vmcnt drained -> new A resident
      }
    }
  }

  // ---- fused finalize: last block to finish computes the loss ----
  __threadfence();  // device-scope: den/posAcc atomics visible
  if (tid == 0) lastFlag = (atomicAdd(done, 1) == NPBLK - 1);
  __syncthreads();
  if (lastFlag) {
    float s = 0.0f;
    for (int i = tid; i < NROW; i += NTHR)
      s += logf(__hip_atomic_load(&den[i], __ATOMIC_RELAXED,
                                  __HIP_MEMORY_SCOPE_AGENT));
#pragma unroll
    for (int off = 1; off < 64; off <<= 1) s += __shfl_xor(s, off);
    if (lane == 0) redbuf[wave] = s;
    __syncthreads();
    if (tid == 0) {
      float tot = redbuf[0] + redbuf[1] + redbuf[2] + redbuf[3];
      const float pos = __hip_atomic_load(posAcc, __ATOMIC_RELAXED,
                                          __HIP_MEMORY_SCOPE_AGENT);
      // each unordered positive pair was counted once -> double it
      out[0] = (tot - 2.0f * pos) * (1.0f / (float)NROW);
    }
  }
}

extern "C" void kernel_launch(void* const* d_in, const int* in_sizes, int n_in,
                              void* d_out, int out_size, void* d_ws, size_t ws_size,
                              hipStream_t stream) {
  const float* zi = (const float*)d_in[0];
  const float* zj = (const float*)d_in[1];
  float* out = (float*)d_out;

  u8* An = (u8*)d_ws;                                      // 4 MB packed fp8
  float* den = (float*)((char*)d_ws + (size_t)NROW * D);   // 8192 fp32
  float* posAcc = den + NROW;                              // 1 fp32
  int* done = (int*)(posAcc + 1);                          // 1 int

  normalize_k<<<NROW / 4, 256, 0, stream>>>(zi, zj, An, den, posAcc, done);
  gemm_expsum<<<NPBLK, NTHR, 0, stream>>>(An, den, posAcc, done, out);
}